// Round 11
// baseline (41.654 us; speedup 1.0000x reference)
//
#include <hip/hip_runtime.h>
#include <math.h>

#define EPSF 1e-6f
#define LOG2E 1.4426950408889634f

__device__ __forceinline__ float sigmoidf_(float v) { return 1.0f / (1.0f + __expf(-v)); }

// LDS layout (floats) for encrho:
//   W1   [0,4096)        w1 stride-8 rows        | Phase A: flt [0,12288)
//   W2   [4096,12288)    w2 stride-8 rows        | Phase A: flt
//   W3   [0,8192)        w3 stride-8 (after conv2)
//   SIN  [12288,12800)   sIn [16][32]
//   SH1  [12800,13696)   [32][28]
//   SH2  [13696,14464)   [32][24]
//   SH3T [14464,15104)   [20][32] transposed
//   RED  [15104,16640)   [8][32][6]
//   TOT  [16640,16832)   [32][6]
//   RNG  [16832,16838)
// total 16840 floats = 67360 B -> 2 blocks/CU
#define W1OFF   0
#define W2OFF   4096
#define W3OFF   0
#define SINOFF  12288
#define SH1OFF  12800
#define SH2OFF  13696
#define SH3TOFF 14464
#define REDOFF  15104
#define TOTOFF  16640
#define RNGOFF  16832

__global__ __launch_bounds__(512, 1) void encrho_kernel(
    const float* __restrict__ x, const float* __restrict__ y,
    const float* __restrict__ xg, const float* __restrict__ enc_sigma,
    const float* __restrict__ gW, const float* __restrict__ gb,
    const float* __restrict__ w1, const float* __restrict__ b1,
    const float* __restrict__ w2, const float* __restrict__ b2,
    const float* __restrict__ w3, const float* __restrict__ b3,
    const float* __restrict__ linW, const float* __restrict__ linb,
    float* __restrict__ mu_t, float* __restrict__ stdv_t,
    int nb, int M)
{
    __shared__ __align__(16) float smem[16840];
    __shared__ int scnt[3];
    __shared__ int spad[3];
    float* flt = smem;

    const int tid = threadIdx.x;
    const int lane = tid & 63;
    const int b = blockIdx.y;
    const int c0 = blockIdx.x * 20;
    const int ic = tid & 31, ng = tid >> 5;

    // ---------------- Phase A: filtered encoder over 32 cols ----------------
    {
        float sg0 = __expf(enc_sigma[0]) + EPSF;
        float sg1 = __expf(enc_sigma[1]) + EPSF;
        float sg2 = __expf(enc_sigma[2]) + EPSF;
        float e20 = -0.5f * LOG2E / (sg0 * sg0);
        float e21 = -0.5f * LOG2E / (sg1 * sg1);
        float e22 = -0.5f * LOG2E / (sg2 * sg2);

        int mg = c0 - 6 + ic;
        bool cv = (mg >= 0 && mg < M);
        float g0 = 0, g1 = 0, g2 = 0;
        if (cv) {
            const float* gp = xg + (size_t)(b * M + mg) * 3;
            g0 = gp[0]; g1 = gp[1]; g2 = gp[2];
        }
        if (tid < 3) scnt[tid] = 0;
        if (tid < 96) {
            int c = tid >> 5;
            int col = c0 - 6 + ic;
            col = col < 0 ? 0 : (col >= M ? M - 1 : col);
            float gv = xg[(size_t)(b * M + col) * 3 + c];
            float gmn = gv, gmx = gv;
            #pragma unroll
            for (int mask = 1; mask <= 16; mask <<= 1) {
                gmn = fminf(gmn, __shfl_xor(gmn, mask, 64));
                gmx = fmaxf(gmx, __shfl_xor(gmx, mask, 64));
            }
            if (ic == 0) {
                float sgc = __expf(enc_sigma[c]) + EPSF;
                smem[RNGOFF + c] = gmn - 10.0f * sgc;
                smem[RNGOFF + 3 + c] = gmx + 10.0f * sgc;
            }
        }
        __syncthreads();
        // filter pass: ballot-aggregated append per channel
        {
            const float* xb = x + (size_t)b * 6144;
            const float* yb = y + (size_t)b * 6144;
            for (int base = 0; base < 6144; base += 512) {
                int idx = base + tid;
                float xv = xb[idx];
                float yv = yb[idx];
                int c = idx % 3;
                bool pass = (xv >= smem[RNGOFF + c] && xv <= smem[RNGOFF + 3 + c]);
                #pragma unroll
                for (int t = 0; t < 3; t++) {
                    unsigned long long mball = __ballot(pass && (c == t));
                    int bpos = 0;
                    if (lane == 0) bpos = atomicAdd(&scnt[t], __popcll(mball));
                    bpos = __shfl(bpos, 0, 64);
                    if (pass && (c == t)) {
                        int pos = bpos + __popcll(mball & ((1ull << lane) - 1ull));
                        int o = (t << 12) + (pos << 1);
                        flt[o] = xv;
                        flt[o + 1] = yv;
                    }
                }
            }
        }
        __syncthreads();
        if (tid < 3) spad[tid] = (scnt[tid] + 31) & ~31;
        __syncthreads();
        #pragma unroll
        for (int c = 0; c < 3; c++) {
            int cnt = scnt[c], cp = spad[c];
            for (int p = cnt + tid; p < cp; p += 512) {
                int o = (c << 12) + (p << 1);
                flt[o] = 1e30f;
                flt[o + 1] = 0.0f;
            }
        }
        __syncthreads();
        float h[6];
        {
            const float2* f = (const float2*)flt;
            int cp = spad[0];
            float s0a = 0, s0b = 0, s1a = 0, s1b = 0;
            #pragma unroll 2
            for (int n = ng; n < cp; n += 32) {
                float2 va = f[n], vb = f[n + 16];
                float da = va.x - g0; float wa = exp2f(e20 * da * da);
                float db = vb.x - g0; float wb = exp2f(e20 * db * db);
                s0a += wa; s1a = fmaf(va.y, wa, s1a);
                s0b += wb; s1b = fmaf(vb.y, wb, s1b);
            }
            h[0] = s0a + s0b; h[3] = s1a + s1b;
        }
        {
            const float2* f = (const float2*)flt + 2048;
            int cp = spad[1];
            float s0a = 0, s0b = 0, s1a = 0, s1b = 0;
            #pragma unroll 2
            for (int n = ng; n < cp; n += 32) {
                float2 va = f[n], vb = f[n + 16];
                float da = va.x - g1; float wa = exp2f(e21 * da * da);
                float db = vb.x - g1; float wb = exp2f(e21 * db * db);
                s0a += wa; s1a = fmaf(va.y, wa, s1a);
                s0b += wb; s1b = fmaf(vb.y, wb, s1b);
            }
            h[1] = s0a + s0b; h[4] = s1a + s1b;
        }
        {
            const float2* f = (const float2*)flt + 4096;
            int cp = spad[2];
            float s0a = 0, s0b = 0, s1a = 0, s1b = 0;
            #pragma unroll 2
            for (int n = ng; n < cp; n += 32) {
                float2 va = f[n], vb = f[n + 16];
                float da = va.x - g2; float wa = exp2f(e22 * da * da);
                float db = vb.x - g2; float wb = exp2f(e22 * db * db);
                s0a += wa; s1a = fmaf(va.y, wa, s1a);
                s0b += wb; s1b = fmaf(vb.y, wb, s1b);
            }
            h[2] = s0a + s0b; h[5] = s1a + s1b;
        }
        __syncthreads();   // flt dead; W1/W2 regions reusable
        #pragma unroll
        for (int c = 0; c < 6; c++) h[c] += __shfl_xor(h[c], 32, 64);
        int wv = tid >> 6;
        if (lane < 32) {
            float* rp = smem + REDOFF + wv * 192 + lane * 6;
            #pragma unroll
            for (int c = 0; c < 6; c++) rp[c] = h[c];
        }
        // stage w1 and w2 into stride-8 rows
        {
            const float4* w1v4 = (const float4*)w1;   // 640
            const float4* w2v4 = (const float4*)w2;   // 1280
            #pragma unroll 1
            for (int i4 = tid; i4 < 640; i4 += 512) {
                float4 v = w1v4[i4];
                float vv[4] = {v.x, v.y, v.z, v.w};
                #pragma unroll
                for (int j = 0; j < 4; j++) {
                    int e = 4 * i4 + j;
                    int row = e / 5;
                    smem[W1OFF + row * 8 + (e - row * 5)] = vv[j];
                }
            }
            #pragma unroll 1
            for (int i4 = tid; i4 < 1280; i4 += 512) {
                float4 v = w2v4[i4];
                float vv[4] = {v.x, v.y, v.z, v.w};
                #pragma unroll
                for (int j = 0; j < 4; j++) {
                    int e = 4 * i4 + j;
                    int row = e / 5;
                    smem[W2OFF + row * 8 + (e - row * 5)] = vv[j];
                }
            }
        }
        __syncthreads();
        if (tid < 192) {
            int ic2 = tid & 31, c = tid >> 5;
            float s = 0.0f;
            #pragma unroll
            for (int w = 0; w < 8; w++) s += smem[REDOFF + w * 192 + ic2 * 6 + c];
            smem[TOTOFF + ic2 * 6 + c] = s;
        }
        __syncthreads();
        {
            int j = tid >> 5, ic2 = tid & 31;
            int mg2 = c0 - 6 + ic2;
            float v = 0.0f;
            if (mg2 >= 0 && mg2 < M) {
                const float* tp = smem + TOTOFF + ic2 * 6;
                float cat[6];
                #pragma unroll
                for (int c = 0; c < 3; c++) {
                    cat[c] = tp[c];
                    cat[3 + c] = tp[3 + c] / (tp[c] + EPSF);
                }
                float r = gb[j];
                #pragma unroll
                for (int i = 0; i < 6; i++) r = fmaf(cat[i], gW[i * 16 + j], r);
                v = sigmoidf_(r);
            }
            smem[SINOFF + j * 32 + ic2] = v;
        }
    }
    __syncthreads();

    // ---------------- Phase B: rho CNN (wide-LDS tiling) + head ----------------
    {
        // conv1: 28 cols x 32 o; thread (o2<16, cg<14) -> o=2o2..+1, q=2cg..+1
        if (tid < 224) {
            int o2 = tid / 14, cg = tid - o2 * 14;
            int oA = o2 * 2, oB = oA + 1;
            float aA0 = b1[oA], aA1 = aA0;
            float aB0 = b1[oB], aB1 = aB0;
            #pragma unroll 2
            for (int i = 0; i < 16; i++) {
                const float* ip = smem + SINOFF + i * 32 + 2 * cg;
                float2 f01 = *(const float2*)ip;
                float2 f23 = *(const float2*)(ip + 2);
                float2 f45 = *(const float2*)(ip + 4);
                const float* wA = smem + W1OFF + (oA * 16 + i) * 8;
                const float* wB = smem + W1OFF + (oB * 16 + i) * 8;
                float4 wa = *(const float4*)wA; float wa4 = wA[4];
                float4 wb = *(const float4*)wB; float wb4 = wB[4];
                aA0 = fmaf(f01.x, wa.x, aA0); aA0 = fmaf(f01.y, wa.y, aA0);
                aA0 = fmaf(f23.x, wa.z, aA0); aA0 = fmaf(f23.y, wa.w, aA0);
                aA0 = fmaf(f45.x, wa4, aA0);
                aA1 = fmaf(f01.y, wa.x, aA1); aA1 = fmaf(f23.x, wa.y, aA1);
                aA1 = fmaf(f23.y, wa.z, aA1); aA1 = fmaf(f45.x, wa.w, aA1);
                aA1 = fmaf(f45.y, wa4, aA1);
                aB0 = fmaf(f01.x, wb.x, aB0); aB0 = fmaf(f01.y, wb.y, aB0);
                aB0 = fmaf(f23.x, wb.z, aB0); aB0 = fmaf(f23.y, wb.w, aB0);
                aB0 = fmaf(f45.x, wb4, aB0);
                aB1 = fmaf(f01.y, wb.x, aB1); aB1 = fmaf(f23.x, wb.y, aB1);
                aB1 = fmaf(f23.y, wb.z, aB1); aB1 = fmaf(f45.x, wb.w, aB1);
                aB1 = fmaf(f45.y, wb4, aB1);
            }
            int q = 2 * cg;
            int gq = c0 - 4 + q;
            bool v0 = (gq >= 0 && gq < M), v1 = (gq + 1 >= 0 && gq + 1 < M);
            smem[SH1OFF + oA * 28 + q]     = v0 ? fmaxf(aA0, 0.f) : 0.f;
            smem[SH1OFF + oA * 28 + q + 1] = v1 ? fmaxf(aA1, 0.f) : 0.f;
            smem[SH1OFF + oB * 28 + q]     = v0 ? fmaxf(aB0, 0.f) : 0.f;
            smem[SH1OFF + oB * 28 + q + 1] = v1 ? fmaxf(aB1, 0.f) : 0.f;
        }
        __syncthreads();
        // w3 early-load: global -> regs; LDS write after conv2
        float4 wreg0, wreg1, wreg2;
        {
            const float4* w3v = (const float4*)w3;   // 1280
            wreg0 = w3v[tid];
            wreg1 = w3v[tid + 512];
            if (tid < 256) wreg2 = w3v[tid + 1024];
        }
        // conv2: 24 cols x 32 o; thread (o2<16, cg<12)
        if (tid < 192) {
            int o2 = tid / 12, cg = tid - o2 * 12;
            int oA = o2 * 2, oB = oA + 1;
            float aA0 = b2[oA], aA1 = aA0;
            float aB0 = b2[oB], aB1 = aB0;
            #pragma unroll 2
            for (int i = 0; i < 32; i++) {
                const float* ip = smem + SH1OFF + i * 28 + 2 * cg;
                float2 f01 = *(const float2*)ip;
                float2 f23 = *(const float2*)(ip + 2);
                float2 f45 = *(const float2*)(ip + 4);
                const float* wA = smem + W2OFF + (oA * 32 + i) * 8;
                const float* wB = smem + W2OFF + (oB * 32 + i) * 8;
                float4 wa = *(const float4*)wA; float wa4 = wA[4];
                float4 wb = *(const float4*)wB; float wb4 = wB[4];
                aA0 = fmaf(f01.x, wa.x, aA0); aA0 = fmaf(f01.y, wa.y, aA0);
                aA0 = fmaf(f23.x, wa.z, aA0); aA0 = fmaf(f23.y, wa.w, aA0);
                aA0 = fmaf(f45.x, wa4, aA0);
                aA1 = fmaf(f01.y, wa.x, aA1); aA1 = fmaf(f23.x, wa.y, aA1);
                aA1 = fmaf(f23.y, wa.z, aA1); aA1 = fmaf(f45.x, wa.w, aA1);
                aA1 = fmaf(f45.y, wa4, aA1);
                aB0 = fmaf(f01.x, wb.x, aB0); aB0 = fmaf(f01.y, wb.y, aB0);
                aB0 = fmaf(f23.x, wb.z, aB0); aB0 = fmaf(f23.y, wb.w, aB0);
                aB0 = fmaf(f45.x, wb4, aB0);
                aB1 = fmaf(f01.y, wb.x, aB1); aB1 = fmaf(f23.x, wb.y, aB1);
                aB1 = fmaf(f23.y, wb.z, aB1); aB1 = fmaf(f45.x, wb.w, aB1);
                aB1 = fmaf(f45.y, wb4, aB1);
            }
            int q = 2 * cg;
            int gq = c0 - 2 + q;
            bool v0 = (gq >= 0 && gq < M), v1 = (gq + 1 >= 0 && gq + 1 < M);
            smem[SH2OFF + oA * 24 + q]     = v0 ? fmaxf(aA0, 0.f) : 0.f;
            smem[SH2OFF + oA * 24 + q + 1] = v1 ? fmaxf(aA1, 0.f) : 0.f;
            smem[SH2OFF + oB * 24 + q]     = v0 ? fmaxf(aB0, 0.f) : 0.f;
            smem[SH2OFF + oB * 24 + q + 1] = v1 ? fmaxf(aB1, 0.f) : 0.f;
        }
        // write w3 into W3 (stride-8 rows)
        {
            float vv0[4] = {wreg0.x, wreg0.y, wreg0.z, wreg0.w};
            #pragma unroll
            for (int j = 0; j < 4; j++) {
                int e = 4 * tid + j;
                int row = e / 5;
                smem[W3OFF + row * 8 + (e - row * 5)] = vv0[j];
            }
            float vv1[4] = {wreg1.x, wreg1.y, wreg1.z, wreg1.w};
            #pragma unroll
            for (int j = 0; j < 4; j++) {
                int e = 4 * (tid + 512) + j;
                int row = e / 5;
                smem[W3OFF + row * 8 + (e - row * 5)] = vv1[j];
            }
            if (tid < 256) {
                float vv2[4] = {wreg2.x, wreg2.y, wreg2.z, wreg2.w};
                #pragma unroll
                for (int j = 0; j < 4; j++) {
                    int e = 4 * (tid + 1024) + j;
                    int row = e / 5;
                    smem[W3OFF + row * 8 + (e - row * 5)] = vv2[j];
                }
            }
        }
        __syncthreads();
        // conv3: 20 cols x 32 o; thread (o2<16, cg<10); writes transposed sH3t
        if (tid < 160) {
            int o2 = tid / 10, cg = tid - o2 * 10;
            int oA = o2 * 2, oB = oA + 1;
            float aA0 = b3[oA], aA1 = aA0;
            float aB0 = b3[oB], aB1 = aB0;
            #pragma unroll 2
            for (int i = 0; i < 32; i++) {
                const float* ip = smem + SH2OFF + i * 24 + 2 * cg;
                float2 f01 = *(const float2*)ip;
                float2 f23 = *(const float2*)(ip + 2);
                float2 f45 = *(const float2*)(ip + 4);
                const float* wA = smem + W3OFF + (oA * 32 + i) * 8;
                const float* wB = smem + W3OFF + (oB * 32 + i) * 8;
                float4 wa = *(const float4*)wA; float wa4 = wA[4];
                float4 wb = *(const float4*)wB; float wb4 = wB[4];
                aA0 = fmaf(f01.x, wa.x, aA0); aA0 = fmaf(f01.y, wa.y, aA0);
                aA0 = fmaf(f23.x, wa.z, aA0); aA0 = fmaf(f23.y, wa.w, aA0);
                aA0 = fmaf(f45.x, wa4, aA0);
                aA1 = fmaf(f01.y, wa.x, aA1); aA1 = fmaf(f23.x, wa.y, aA1);
                aA1 = fmaf(f23.y, wa.z, aA1); aA1 = fmaf(f45.x, wa.w, aA1);
                aA1 = fmaf(f45.y, wa4, aA1);
                aB0 = fmaf(f01.x, wb.x, aB0); aB0 = fmaf(f01.y, wb.y, aB0);
                aB0 = fmaf(f23.x, wb.z, aB0); aB0 = fmaf(f23.y, wb.w, aB0);
                aB0 = fmaf(f45.x, wb4, aB0);
                aB1 = fmaf(f01.y, wb.x, aB1); aB1 = fmaf(f23.x, wb.y, aB1);
                aB1 = fmaf(f23.y, wb.z, aB1); aB1 = fmaf(f45.x, wb.w, aB1);
                aB1 = fmaf(f45.y, wb4, aB1);
            }
            int q = 2 * cg;
            smem[SH3TOFF + q * 32 + oA]       = aA0;
            smem[SH3TOFF + (q + 1) * 32 + oA] = aA1;
            smem[SH3TOFF + q * 32 + oB]       = aB0;
            smem[SH3TOFF + (q + 1) * 32 + oB] = aB1;
        }
        __syncthreads();
        // head: 20 cols x 30 outs; writes TRANSPOSED planes (b, k, M)
        #pragma unroll 1
        for (int idx = tid; idx < 600; idx += 512) {
            int q = idx / 30, j = idx - (idx / 30) * 30;
            int m = c0 + q;
            if (m < M) {
                const float* hp = smem + SH3TOFF + q * 32;
                float v = linb[j];
                #pragma unroll
                for (int o4 = 0; o4 < 8; o4++) {
                    float4 h4 = *(const float4*)(hp + o4 * 4);
                    const float* lw = linW + o4 * 4 * 30 + j;
                    v = fmaf(h4.x, lw[0], v);
                    v = fmaf(h4.y, lw[30], v);
                    v = fmaf(h4.z, lw[60], v);
                    v = fmaf(h4.w, lw[90], v);
                }
                if (j < 15) mu_t[((size_t)b * 15 + j) * M + m] = v;
                else        stdv_t[((size_t)b * 15 + (j - 15)) * M + m] = 0.1f + 0.9f * sigmoidf_(v);
            }
        }
    }
}

// ---------------- K2: windowed interpolation, coalesced transposed planes ----------------
// block 256 = 8 targets (ti=tid>>5) x 32 m-lanes (mg=tid&31); grid (ceil(ntar/8), nb)
__global__ __launch_bounds__(256, 4) void final_kernel(
    const float* __restrict__ x_out, const float* __restrict__ xg,
    const float* __restrict__ int_sigma, const float* __restrict__ eps,
    const float* __restrict__ mu_t, const float* __restrict__ stdv_t,
    const float* __restrict__ loW, const float* __restrict__ lob,
    float* __restrict__ out, int nb, int ntar, int M)
{
    __shared__ float AB[8][30];
    int b = blockIdx.y;
    int tt = blockIdx.x * 8;
    int tid = threadIdx.x;
    int mg = tid & 31, ti = tid >> 5;
    int t = tt + ti;
    bool tv = (t < ntar);
    float xt[3];
    #pragma unroll
    for (int c = 0; c < 3; c++) xt[c] = tv ? x_out[((size_t)b * ntar + t) * 3 + c] : 0.0f;
    float k2[15], Wc[3] = {0, 0, 0};
    #pragma unroll
    for (int k = 0; k < 15; k++) {
        float isc = __expf(int_sigma[k]) + EPSF;
        k2[k] = -0.5f * LOG2E / (isc * isc);
        Wc[k % 3] = fmaxf(Wc[k % 3], 10.0f * isc);
    }
    float gg0 = xg[(size_t)b * M * 3];
    float ggL = xg[((size_t)b * M + (M - 1)) * 3];
    float Dx = (ggL - gg0) / (float)(M - 1);
    float invDx = 1.0f / Dx;
    float A[15], B[15];
    #pragma unroll
    for (int k = 0; k < 15; k++) { A[k] = 0.0f; B[k] = 0.0f; }
    #pragma unroll
    for (int c = 0; c < 3; c++) {
        float xtc = xt[c];
        int lo = (int)floorf((xtc - Wc[c] - gg0) * invDx) - 1;
        int hi = (int)ceilf((xtc + Wc[c] - gg0) * invDx) + 1;
        lo = lo < 0 ? 0 : lo;
        hi = hi > M - 1 ? M - 1 : hi;
        const float* pm0 = mu_t + ((size_t)b * 15 + c) * M;
        const float* pm1 = pm0 + 3 * M;
        const float* pm2 = pm0 + 6 * M;
        const float* pm3 = pm0 + 9 * M;
        const float* pm4 = pm0 + 12 * M;
        const float* ps0 = stdv_t + ((size_t)b * 15 + c) * M;
        const float* ps1 = ps0 + 3 * M;
        const float* ps2 = ps0 + 6 * M;
        const float* ps3 = ps0 + 9 * M;
        const float* ps4 = ps0 + 12 * M;
        #pragma unroll 1
        for (int m = lo + mg; m <= hi; m += 32) {
            float d = (gg0 + m * Dx) - xtc;
            float d2 = d * d;
            float w0 = exp2f(k2[c] * d2);
            float w1v = exp2f(k2[c + 3] * d2);
            float w2v = exp2f(k2[c + 6] * d2);
            float w3v = exp2f(k2[c + 9] * d2);
            float w4v = exp2f(k2[c + 12] * d2);
            A[c]      = fmaf(pm0[m], w0, A[c]);       B[c]      = fmaf(ps0[m], w0, B[c]);
            A[c + 3]  = fmaf(pm1[m], w1v, A[c + 3]);  B[c + 3]  = fmaf(ps1[m], w1v, B[c + 3]);
            A[c + 6]  = fmaf(pm2[m], w2v, A[c + 6]);  B[c + 6]  = fmaf(ps2[m], w2v, B[c + 6]);
            A[c + 9]  = fmaf(pm3[m], w3v, A[c + 9]);  B[c + 9]  = fmaf(ps3[m], w3v, B[c + 9]);
            A[c + 12] = fmaf(pm4[m], w4v, A[c + 12]); B[c + 12] = fmaf(ps4[m], w4v, B[c + 12]);
        }
    }
    #pragma unroll
    for (int mask = 1; mask <= 16; mask <<= 1) {
        #pragma unroll
        for (int k = 0; k < 15; k++) {
            A[k] += __shfl_xor(A[k], mask, 64);
            B[k] += __shfl_xor(B[k], mask, 64);
        }
    }
    if (mg == 0) {
        #pragma unroll
        for (int k = 0; k < 15; k++) { AB[ti][k] = A[k]; AB[ti][15 + k] = B[k]; }
    }
    __syncthreads();
    if (tid < 192) {
        int t2 = tid / 24;
        int rem = tid - t2 * 24;
        int s = rem / 6, j = rem - s * 6;
        int tg = tt + t2;
        if (tg < ntar) {
            float val = lob[j];
            const float* ep = eps + ((size_t)s * nb + b) * 15;
            #pragma unroll
            for (int k = 0; k < 15; k++) {
                float h = fmaf(ep[k], AB[t2][15 + k], AB[t2][k]);
                val = fmaf(h, loW[k * 6 + j], val);
            }
            if (j >= 3) val = fmaxf(val, 0.0f) + log1pf(__expf(-fabsf(val)));  // softplus
            out[(((size_t)s * nb + b) * ntar + tg) * 6 + j] = val;
        }
    }
}

// =====================================================================
// Fallback path (generic shapes) — head writes transposed planes
// =====================================================================

__global__ __launch_bounds__(1024) void enc_kernel_g(
    const float* __restrict__ x, const float* __restrict__ y,
    const float* __restrict__ xg, const float* __restrict__ enc_sigma,
    const float* __restrict__ gW, const float* __restrict__ gb,
    float* __restrict__ rep_s, int nb, int npts, int M)
{
    __shared__ float sx[6144];
    __shared__ float sy[6144];
    __shared__ float red[16][8][6];
    __shared__ float tot[8][6];
    int b = blockIdx.y;
    int mt = blockIdx.x * 8;
    int tid = threadIdx.x;
    int n3 = npts * 3;
    if (n3 > 6144) n3 = 6144;
    for (int i = tid; i < n3; i += 1024) {
        sx[i] = x[(size_t)b * npts * 3 + i];
        sy[i] = y[(size_t)b * npts * 3 + i];
    }
    int npts_l = n3 / 3;
    int mi = tid & 7, ng = tid >> 3;
    int m = mt + mi;
    bool mv = (m < M);
    float e1[3], g[3];
    for (int c = 0; c < 3; c++) {
        float inv = 1.0f / (__expf(enc_sigma[c]) + EPSF);
        e1[c] = -0.5f * inv * inv;
    }
    for (int c = 0; c < 3; c++) g[c] = mv ? xg[(size_t)(b * M + m) * 3 + c] : 0.0f;
    __syncthreads();
    float h0[3] = {0,0,0}, h1[3] = {0,0,0};
    for (int n = ng; n < npts_l; n += 128) {
        for (int c = 0; c < 3; c++) {
            float d = sx[n * 3 + c] - g[c];
            float w = __expf(e1[c] * d * d);
            h0[c] += w;
            h1[c] = fmaf(sy[n * 3 + c], w, h1[c]);
        }
    }
    for (int mask = 8; mask <= 32; mask <<= 1) {
        for (int c = 0; c < 3; c++) {
            h0[c] += __shfl_xor(h0[c], mask, 64);
            h1[c] += __shfl_xor(h1[c], mask, 64);
        }
    }
    int lane = tid & 63, wv = tid >> 6;
    if (lane < 8) {
        for (int c = 0; c < 3; c++) { red[wv][lane][c] = h0[c]; red[wv][lane][3 + c] = h1[c]; }
    }
    __syncthreads();
    if (tid < 48) {
        int mi2 = tid & 7, c2 = tid >> 3;
        float s = 0.0f;
        for (int k = 0; k < 16; k++) s += red[k][mi2][c2];
        tot[mi2][c2] = s;
    }
    __syncthreads();
    if (tid < 128) {
        int mi2 = tid & 7, j = tid >> 3;
        int m2 = mt + mi2;
        if (m2 < M) {
            float cat[6];
            for (int c = 0; c < 3; c++) {
                cat[c] = tot[mi2][c];
                cat[3 + c] = tot[mi2][3 + c] / (tot[mi2][c] + EPSF);
            }
            float r = gb[j];
            for (int i = 0; i < 6; i++) r = fmaf(cat[i], gW[i * 16 + j], r);
            rep_s[((size_t)b * 16 + j) * M + m2] = sigmoidf_(r);
        }
    }
}

__global__ __launch_bounds__(256) void rho_kernel_g(
    const float* __restrict__ rep_s,
    const float* __restrict__ w1, const float* __restrict__ b1,
    const float* __restrict__ w2, const float* __restrict__ b2,
    const float* __restrict__ w3, const float* __restrict__ b3,
    const float* __restrict__ linW, const float* __restrict__ linb,
    float* __restrict__ mu_t, float* __restrict__ stdv_t,
    int nb, int M)
{
    __shared__ float sWA[5152];
    __shared__ float sWB[5152];
    __shared__ float sIn[16][20];
    __shared__ float sH1[32][16];
    __shared__ float sH2[32][12];
    __shared__ float sH3[32][8];
    int b = blockIdx.y;
    int t0 = blockIdx.x * 8;
    int tid = threadIdx.x;
    {
        const float4* w1v = (const float4*)w1;
        const float4* w2v = (const float4*)w2;
        for (int i4 = tid; i4 < 640; i4 += 256) {
            float4 v = w1v[i4];
            float vv[4] = {v.x, v.y, v.z, v.w};
            for (int j = 0; j < 4; j++) {
                int e = 4 * i4 + j;
                sWA[(e / 80) * 81 + e % 80] = vv[j];
            }
        }
        for (int i4 = tid; i4 < 1280; i4 += 256) {
            float4 v = w2v[i4];
            float vv[4] = {v.x, v.y, v.z, v.w};
            for (int j = 0; j < 4; j++) {
                int e = 4 * i4 + j;
                sWB[(e / 160) * 161 + e % 160] = vv[j];
            }
        }
        for (int idx = tid; idx < 16 * 20; idx += 256) {
            int i = idx / 20, q = idx % 20;
            int mg = t0 - 6 + q;
            sIn[i][q] = (mg >= 0 && mg < M) ? rep_s[((size_t)b * 16 + i) * M + mg] : 0.0f;
        }
    }
    __syncthreads();
    int o = tid >> 3, q0 = tid & 7;
    {
        float a0 = b1[o], a1 = a0;
        #pragma unroll 2
        for (int i = 0; i < 16; i++) {
            const float* wp = sWA + o * 81 + i * 5;
            float u0 = wp[0], u1 = wp[1], u2 = wp[2], u3 = wp[3], u4 = wp[4];
            const float* ip = &sIn[i][0];
            a0 = fmaf(ip[q0], u0, a0);      a0 = fmaf(ip[q0+1], u1, a0);
            a0 = fmaf(ip[q0+2], u2, a0);    a0 = fmaf(ip[q0+3], u3, a0);
            a0 = fmaf(ip[q0+4], u4, a0);
            a1 = fmaf(ip[q0+8], u0, a1);    a1 = fmaf(ip[q0+9], u1, a1);
            a1 = fmaf(ip[q0+10], u2, a1);   a1 = fmaf(ip[q0+11], u3, a1);
            a1 = fmaf(ip[q0+12], u4, a1);
        }
        int g0 = t0 - 4 + q0, g1 = g0 + 8;
        sH1[o][q0]     = (g0 >= 0 && g0 < M) ? fmaxf(a0, 0.0f) : 0.0f;
        sH1[o][q0 + 8] = (g1 >= 0 && g1 < M) ? fmaxf(a1, 0.0f) : 0.0f;
    }
    __syncthreads();
    float4 wreg[5];
    {
        const float4* w3v = (const float4*)w3;
        for (int h = 0; h < 5; h++) wreg[h] = w3v[tid + 256 * h];
    }
    {
        float a0 = b2[o], a1 = a0;
        bool second = (q0 < 4);
        #pragma unroll 2
        for (int i = 0; i < 32; i++) {
            const float* wp = sWB + o * 161 + i * 5;
            float u0 = wp[0], u1 = wp[1], u2 = wp[2], u3 = wp[3], u4 = wp[4];
            const float* ip = &sH1[i][0];
            a0 = fmaf(ip[q0], u0, a0);      a0 = fmaf(ip[q0+1], u1, a0);
            a0 = fmaf(ip[q0+2], u2, a0);    a0 = fmaf(ip[q0+3], u3, a0);
            a0 = fmaf(ip[q0+4], u4, a0);
            if (second) {
                a1 = fmaf(ip[q0+8], u0, a1);    a1 = fmaf(ip[q0+9], u1, a1);
                a1 = fmaf(ip[q0+10], u2, a1);   a1 = fmaf(ip[q0+11], u3, a1);
                a1 = fmaf(ip[q0+12], u4, a1);
            }
        }
        int g0 = t0 - 2 + q0, g1 = g0 + 8;
        sH2[o][q0] = (g0 >= 0 && g0 < M) ? fmaxf(a0, 0.0f) : 0.0f;
        if (second) sH2[o][q0 + 8] = (g1 >= 0 && g1 < M) ? fmaxf(a1, 0.0f) : 0.0f;
    }
    for (int h = 0; h < 5; h++) {
        float vv[4] = {wreg[h].x, wreg[h].y, wreg[h].z, wreg[h].w};
        for (int j = 0; j < 4; j++) {
            int e = 4 * (tid + 256 * h) + j;
            sWA[(e / 160) * 161 + e % 160] = vv[j];
        }
    }
    __syncthreads();
    {
        float a0 = b3[o];
        #pragma unroll 2
        for (int i = 0; i < 32; i++) {
            const float* wp = sWA + o * 161 + i * 5;
            float u0 = wp[0], u1 = wp[1], u2 = wp[2], u3 = wp[3], u4 = wp[4];
            const float* ip = &sH2[i][0];
            a0 = fmaf(ip[q0], u0, a0);      a0 = fmaf(ip[q0+1], u1, a0);
            a0 = fmaf(ip[q0+2], u2, a0);    a0 = fmaf(ip[q0+3], u3, a0);
            a0 = fmaf(ip[q0+4], u4, a0);
        }
        sH3[o][q0] = a0;
    }
    __syncthreads();
    if (tid < 240) {
        int q = tid / 30, j = tid % 30;
        int m = t0 + q;
        if (m < M) {
            float v = linb[j];
            #pragma unroll 8
            for (int oo = 0; oo < 32; oo++) v = fmaf(sH3[oo][q], linW[oo * 30 + j], v);
            if (j < 15) mu_t[((size_t)b * 15 + j) * M + m] = v;
            else        stdv_t[((size_t)b * 15 + (j - 15)) * M + m] = 0.1f + 0.9f * sigmoidf_(v);
        }
    }
}

extern "C" void kernel_launch(void* const* d_in, const int* in_sizes, int n_in,
                              void* d_out, int out_size, void* d_ws, size_t ws_size,
                              hipStream_t stream)
{
    const float* x         = (const float*)d_in[0];
    const float* y         = (const float*)d_in[1];
    const float* x_out     = (const float*)d_in[2];
    const float* x_grid    = (const float*)d_in[3];
    const float* eps_noise = (const float*)d_in[4];
    const float* enc_sigma = (const float*)d_in[5];
    const float* gW        = (const float*)d_in[6];
    const float* gb        = (const float*)d_in[7];
    const float* w1        = (const float*)d_in[8];
    const float* b1        = (const float*)d_in[9];
    const float* w2        = (const float*)d_in[10];
    const float* b2        = (const float*)d_in[11];
    const float* w3        = (const float*)d_in[12];
    const float* b3        = (const float*)d_in[13];
    const float* linW      = (const float*)d_in[14];
    const float* linb      = (const float*)d_in[15];
    const float* int_sigma = (const float*)d_in[16];
    const float* loW       = (const float*)d_in[17];
    const float* lob       = (const float*)d_in[18];
    float* out = (float*)d_out;

    const int NS = 4, C = 3, NBASIS = 5;
    int nb   = in_sizes[4] / (NS * C * NBASIS);       // eps_noise: (NS, nb, 15)
    int npts = in_sizes[0] / (nb * C);
    int ntar = in_sizes[2] / (nb * C);
    int M    = in_sizes[3] / (nb * C);

    float* mu_t   = (float*)d_ws;                      // (nb, 15, M) planes
    float* stdv_t = mu_t + (size_t)nb * 15 * M;        // (nb, 15, M)

    bool fast = (npts == 2048 && M <= 320);
    if (fast) {
        encrho_kernel<<<dim3(16, nb), 512, 0, stream>>>(
            x, y, x_grid, enc_sigma, gW, gb,
            w1, b1, w2, b2, w3, b3, linW, linb, mu_t, stdv_t, nb, M);
    } else {
        float* rep_s = stdv_t + (size_t)nb * 15 * M;   // (nb, 16, M)
        enc_kernel_g<<<dim3((M + 7) / 8, nb), 1024, 0, stream>>>(
            x, y, x_grid, enc_sigma, gW, gb, rep_s, nb, npts, M);
        rho_kernel_g<<<dim3((M + 7) / 8, nb), 256, 0, stream>>>(
            rep_s, w1, b1, w2, b2, w3, b3, linW, linb, mu_t, stdv_t, nb, M);
    }
    final_kernel<<<dim3((ntar + 7) / 8, nb), 256, 0, stream>>>(
        x_out, x_grid, int_sigma, eps_noise, mu_t, stdv_t, loW, lob, out, nb, ntar, M);
}